// Round 5
// baseline (251.798 us; speedup 1.0000x reference)
//
#include <hip/hip_runtime.h>

typedef __bf16 bf16_t;
typedef __bf16 bf16x8 __attribute__((ext_vector_type(8)));
typedef __bf16 bf16x4 __attribute__((ext_vector_type(4)));
typedef float f32x4 __attribute__((ext_vector_type(4)));
typedef float f32x16 __attribute__((ext_vector_type(16)));

#define MFMA16(a, b, c) __builtin_amdgcn_mfma_f32_16x16x32_bf16((a), (b), (c), 0, 0, 0)
#define MFMA32(a, b, c) __builtin_amdgcn_mfma_f32_32x32x16_bf16((a), (b), (c), 0, 0, 0)

#define GLOAD_LDS16(gsrc, ldst)                                                     \
  __builtin_amdgcn_global_load_lds(                                                 \
      (const __attribute__((address_space(1))) void*)(gsrc),                        \
      (__attribute__((address_space(3))) void*)(ldst), 16, 0, 0)

// ---------------------------------------------------------------------------
// Cast fp32 -> bf16 for all 7 arrays in one dispatch.
// ---------------------------------------------------------------------------
__global__ __launch_bounds__(256) void cast_all(
    const float* __restrict__ s0, const float* __restrict__ s1, const float* __restrict__ s2,
    const float* __restrict__ s3, const float* __restrict__ s4, const float* __restrict__ s5,
    const float* __restrict__ s6,
    bf16_t* __restrict__ d0, bf16_t* __restrict__ d1, bf16_t* __restrict__ d2,
    bf16_t* __restrict__ d3, bf16_t* __restrict__ d4, bf16_t* __restrict__ d5,
    bf16_t* __restrict__ d6) {
  const int a = blockIdx.y;
  const float* s = a == 0 ? s0 : a == 1 ? s1 : a == 2 ? s2 : a == 3 ? s3
                 : a == 4 ? s4 : a == 5 ? s5 : s6;
  bf16_t* d = a == 0 ? d0 : a == 1 ? d1 : a == 2 ? d2 : a == 3 ? d3
            : a == 4 ? d4 : a == 5 ? d5 : d6;
  const int n = a < 3 ? (2 * 2048 * 1024) : (1024 * 1024);
  int i = (blockIdx.x * 256 + threadIdx.x) * 4;
  if (i >= n) return;
  float4 v = *reinterpret_cast<const float4*>(s + i);
  bf16x4 o;
  o[0] = (bf16_t)v.x; o[1] = (bf16_t)v.y; o[2] = (bf16_t)v.z; o[3] = (bf16_t)v.w;
  *reinterpret_cast<bf16x4*>(d + i) = o;
}

// ---------------------------------------------------------------------------
// NT GEMM core (m97 tile + counted-vmcnt dbuf): C[M,1024] = A*B^T + bias.
// 128x128 tile, BK=32, 4 waves (2x2), each wave 64x64 (4x4 frags 16x16x32).
// Double-buffered global_load_lds; per-iter: stage(next) -> vmcnt(4) ->
// s_barrier -> frags+MFMA -> s_barrier.  Never drains vmcnt to 0.
// ---------------------------------------------------------------------------
template <int OUTF32>
__device__ __forceinline__ void gemm128(
    const bf16_t* __restrict__ A, const bf16_t* __restrict__ B,
    const float* __restrict__ bias, void* __restrict__ Cout,
    int bm, int bn, float scalep, bf16_t* __restrict__ As, bf16_t* __restrict__ Bs) {
  const int tid = threadIdx.x, lane = tid & 63, wid = tid >> 6;
  const int wr = wid >> 1, wc = wid & 1;
  const int l15 = lane & 15, g = lane >> 4;
  f32x4 acc[4][4] = {};

  // staging: 2 instr/array/wave. instr i covers rows (i*64 + wid*16 + lane>>2),
  // 16B granule (lane&3); LDS dest linear.
  const int srow0 = wid * 16 + (lane >> 2);
  const int srow1 = 64 + wid * 16 + (lane >> 2);
  const int sc = (lane & 3) * 8;
  const bf16_t* Ap0 = A + (size_t)(bm + srow0) * 1024 + sc;
  const bf16_t* Ap1 = A + (size_t)(bm + srow1) * 1024 + sc;
  const bf16_t* Bp0 = B + (size_t)(bn + srow0) * 1024 + sc;
  const bf16_t* Bp1 = B + (size_t)(bn + srow1) * 1024 + sc;

  auto stage = [&](int k0, int buf) {
    bf16_t* Ad = As + buf * 4096;
    bf16_t* Bd = Bs + buf * 4096;
    GLOAD_LDS16(Ap0 + k0, Ad + wid * 512);
    GLOAD_LDS16(Ap1 + k0, Ad + 2048 + wid * 512);
    GLOAD_LDS16(Bp0 + k0, Bd + wid * 512);
    GLOAD_LDS16(Bp1 + k0, Bd + 2048 + wid * 512);
  };

  stage(0, 0);
  for (int t = 0; t < 32; t++) {
    const int kn = (t < 31) ? (t + 1) * 32 : 0;
    stage(kn, (t + 1) & 1);
    asm volatile("s_waitcnt vmcnt(4)" ::: "memory");
    __builtin_amdgcn_s_barrier();
    __builtin_amdgcn_sched_barrier(0);
    const bf16_t* Ab = As + (t & 1) * 4096;
    const bf16_t* Bb = Bs + (t & 1) * 4096;
    bf16x8 af[4], bfr[4];
#pragma unroll
    for (int mi = 0; mi < 4; mi++)
      af[mi] = *reinterpret_cast<const bf16x8*>(&Ab[(wr * 64 + mi * 16 + l15) * 32 + g * 8]);
#pragma unroll
    for (int ni = 0; ni < 4; ni++)
      bfr[ni] = *reinterpret_cast<const bf16x8*>(&Bb[(wc * 64 + ni * 16 + l15) * 32 + g * 8]);
    __builtin_amdgcn_s_setprio(1);
#pragma unroll
    for (int mi = 0; mi < 4; mi++)
#pragma unroll
      for (int ni = 0; ni < 4; ni++)
        acc[mi][ni] = MFMA16(af[mi], bfr[ni], acc[mi][ni]);
    __builtin_amdgcn_s_setprio(0);
    __builtin_amdgcn_sched_barrier(0);
    __builtin_amdgcn_s_barrier();
  }

#pragma unroll
  for (int mi = 0; mi < 4; mi++)
#pragma unroll
    for (int ni = 0; ni < 4; ni++) {
      const int row = bm + wr * 64 + mi * 16 + g * 4;
      const int col = bn + wc * 64 + ni * 16 + l15;
      const float bv = bias[col];
#pragma unroll
      for (int r = 0; r < 4; r++) {
        float v = (acc[mi][ni][r] + bv) * scalep;
        if (OUTF32)
          reinterpret_cast<float*>(Cout)[(size_t)(row + r) * 1024 + col] = v;
        else
          reinterpret_cast<bf16_t*>(Cout)[(size_t)(row + r) * 1024 + col] = (bf16_t)v;
      }
    }
}

// Fused Q/K/V projection: 768 blocks (3 x 32m x 8n), bijective XCD swizzle.
__global__ __launch_bounds__(256) void qkv_gemm(
    const bf16_t* __restrict__ qb, const bf16_t* __restrict__ kb, const bf16_t* __restrict__ vb,
    const bf16_t* __restrict__ wqb, const bf16_t* __restrict__ wkb, const bf16_t* __restrict__ wvb,
    const float* __restrict__ bq, const float* __restrict__ bk, const float* __restrict__ bv,
    bf16_t* __restrict__ QP, bf16_t* __restrict__ KP, bf16_t* __restrict__ VP, float qscale) {
  __shared__ bf16_t As[2 * 4096];
  __shared__ bf16_t Bs[2 * 4096];
  const int id = blockIdx.x;
  const int sw = (id & 7) * 96 + (id >> 3);
  const int z = sw >> 8, rem = sw & 255;
  const int by = rem >> 3, bx = rem & 7;
  const bf16_t* A = z == 0 ? qb : z == 1 ? kb : vb;
  const bf16_t* B = z == 0 ? wqb : z == 1 ? wkb : wvb;
  const float* bias = z == 0 ? bq : z == 1 ? bk : bv;
  bf16_t* C = z == 0 ? QP : z == 1 ? KP : VP;
  gemm128<0>(A, B, bias, C, by * 128, bx * 128, z == 0 ? qscale : 1.0f, As, Bs);
}

// Output projection -> fp32, 256 blocks.
__global__ __launch_bounds__(256) void out_gemm(
    const bf16_t* __restrict__ A, const bf16_t* __restrict__ B,
    const float* __restrict__ bias, float* __restrict__ C) {
  __shared__ bf16_t As[2 * 4096];
  __shared__ bf16_t Bs[2 * 4096];
  const int id = blockIdx.x;
  const int sw = (id & 7) * 32 + (id >> 3);
  const int by = sw >> 3, bx = sw & 7;
  gemm128<1>(A, B, bias, C, by * 128, bx * 128, 1.0f, As, Bs);
}

// ---------------------------------------------------------------------------
// V transpose: VT[b*16+h][d][s] = VP[b][s][h*64+d]
// ---------------------------------------------------------------------------
__global__ __launch_bounds__(256) void transpose_v64(
    const bf16_t* __restrict__ VP, bf16_t* __restrict__ VT) {
  __shared__ bf16_t t[64][72];
  const int tid = threadIdx.x;
  const int bh = blockIdx.y, b = bh >> 4, h = bh & 15;
  const int sbase = blockIdx.x * 64;
#pragma unroll
  for (int i = 0; i < 2; i++) {
    int c = tid + i * 256;
    int r = c >> 3, cc = (c & 7) * 8;
    *reinterpret_cast<bf16x8*>(&t[r][cc]) =
        *reinterpret_cast<const bf16x8*>(&VP[(size_t)(b * 2048 + sbase + r) * 1024 + h * 64 + cc]);
  }
  __syncthreads();
#pragma unroll
  for (int i = 0; i < 2; i++) {
    int c = tid + i * 256;
    int d = c >> 3, scc = (c & 7) * 8;
    bf16x8 v;
#pragma unroll
    for (int j = 0; j < 8; j++) v[j] = t[scc + j][d];
    *reinterpret_cast<bf16x8*>(&VT[(size_t)(bh * 64 + d) * 2048 + sbase + scc]) = v;
  }
}

// ---------------------------------------------------------------------------
// Flash attention fwd v4: 32x32x16 MFMA.
// 4 waves, each owns 32 q-rows (QBLK=128); KVBLK=64.
// Swapped QK^T: C[kc][q] with q = lane&31 -> softmax is in-lane + 1 shfl_xor(32).
// Max-free exp2-domain softmax (scores pre-scaled by Q-projection epilogue).
// K/V double-buffered via global_load_lds (pre-swizzled source, XOR-swizzled
// reads), counted vmcnt(4) + raw s_barrier pair per tile.
// ---------------------------------------------------------------------------
__global__ __launch_bounds__(256) void attn_fwd(
    const bf16_t* __restrict__ Q, const bf16_t* __restrict__ K,
    const bf16_t* __restrict__ VT, bf16_t* __restrict__ O) {
  __shared__ bf16_t Kl[2 * 4096];   // [kc][d] tiles, 16 KB
  __shared__ bf16_t Vl[2 * 4096];   // [d][kc] tiles, 16 KB
  __shared__ bf16_t Pl[4][2048];    // per-wave [q][kc], 16 KB
  __shared__ float Sl[4][32];
  const int tid = threadIdx.x, lane = tid & 63, wid = tid >> 6;
  const int l31 = lane & 31, hsel = lane >> 5, l7 = lane & 7;
  const int id = blockIdx.x;
  const int sw = (id & 7) * 64 + (id >> 3);
  const int bh = sw >> 4, qblk = sw & 15;
  const int b = bh >> 4, h = bh & 15;
  const int qbase = qblk * 128;

  // Q B-fragments: lane supplies Q[q=l31][d = ks*16 + hsel*8 + j]
  const int qrow = b * 2048 + qbase + wid * 32 + l31;
  bf16x8 qf[4];
#pragma unroll
  for (int ks = 0; ks < 4; ks++)
    qf[ks] = *reinterpret_cast<const bf16x8*>(
        &Q[(size_t)qrow * 1024 + h * 64 + ks * 16 + hsel * 8]);

  // staging: wave wid covers rows [wid*16, wid*16+16); 2 instrs per array.
  const int srow = lane >> 3;                // 0..7 within 8-row group
  const int sg = (lane & 7) ^ srow;          // pre-swizzled source granule
  const bf16_t* Ksrc = K + (size_t)(b * 2048 + wid * 16 + srow) * 1024 + h * 64 + sg * 8;
  const bf16_t* Vsrc = VT + (size_t)(bh * 64 + wid * 16 + srow) * 2048 + sg * 8;

  auto stage = [&](int kt, int buf) {
    bf16_t* Kd = Kl + buf * 4096 + wid * 1024;
    bf16_t* Vd = Vl + buf * 4096 + wid * 1024;
    GLOAD_LDS16(Ksrc + (size_t)kt * 1024, Kd);
    GLOAD_LDS16(Ksrc + (size_t)(kt + 8) * 1024, Kd + 512);
    GLOAD_LDS16(Vsrc + kt, Vd);
    GLOAD_LDS16(Vsrc + kt + 8 * 2048, Vd + 512);
  };

  float ssum = 0.0f;
  f32x16 oacc[2] = {};

  stage(0, 0);
  for (int t = 0; t < 32; t++) {
    const int ktn = (t < 31) ? (t + 1) * 64 : 0;
    stage(ktn, (t + 1) & 1);
    asm volatile("s_waitcnt vmcnt(4)" ::: "memory");
    __builtin_amdgcn_s_barrier();
    __builtin_amdgcn_sched_barrier(0);
    const bf16_t* Kb = Kl + (t & 1) * 4096;
    const bf16_t* Vb = Vl + (t & 1) * 4096;

    // ---- QK^T: C[kc][q], kc blocks ni*32, K-dim d (4 ks steps of 16)
    f32x16 sacc[2] = {};
    __builtin_amdgcn_s_setprio(1);
#pragma unroll
    for (int ni = 0; ni < 2; ni++)
#pragma unroll
      for (int ks = 0; ks < 4; ks++) {
        bf16x8 kf = *reinterpret_cast<const bf16x8*>(
            &Kb[(ni * 32 + l31) * 64 + ((2 * ks + hsel) ^ l7) * 8]);
        sacc[ni] = MFMA32(kf, qf[ks], sacc[ni]);
      }
    __builtin_amdgcn_s_setprio(0);

    // ---- max-free softmax: P = exp2(score'), row-sum for normalization
    float rs = 0.0f;
#pragma unroll
    for (int ni = 0; ni < 2; ni++)
#pragma unroll
      for (int r = 0; r < 16; r++) {
        float e = exp2f(sacc[ni][r]);
        sacc[ni][r] = e;
        rs += e;
      }
    rs += __shfl_xor(rs, 32);
    ssum += rs;

    // ---- P -> per-wave LDS: kc = ni*32 + a*8 + hsel*4 + (r&3), swizzled granule
#pragma unroll
    for (int ni = 0; ni < 2; ni++)
#pragma unroll
      for (int a = 0; a < 4; a++) {
        bf16x4 pv;
#pragma unroll
        for (int r = 0; r < 4; r++) pv[r] = (bf16_t)sacc[ni][a * 4 + r];
        *reinterpret_cast<bf16x4*>(
            &Pl[wid][l31 * 64 + (((a + 4 * ni) ^ l7) * 8) + hsel * 4]) = pv;
      }

    // ---- PV: O[q][d] += P[q][kc] * V[kc][d]
    __builtin_amdgcn_s_setprio(1);
#pragma unroll
    for (int ks = 0; ks < 4; ks++) {
      bf16x8 pf = *reinterpret_cast<const bf16x8*>(
          &Pl[wid][l31 * 64 + ((2 * ks + hsel) ^ l7) * 8]);
#pragma unroll
      for (int dI = 0; dI < 2; dI++) {
        bf16x8 vf = *reinterpret_cast<const bf16x8*>(
            &Vb[(dI * 32 + l31) * 64 + ((2 * ks + hsel) ^ l7) * 8]);
        oacc[dI] = MFMA32(pf, vf, oacc[dI]);
      }
    }
    __builtin_amdgcn_s_setprio(0);
    __builtin_amdgcn_sched_barrier(0);
    __builtin_amdgcn_s_barrier();
  }

  // ---- epilogue: broadcast 1/ssum via LDS, normalize, store
  if (lane < 32) Sl[wid][l31] = 1.0f / ssum;
  __builtin_amdgcn_s_barrier();  // wave-local would suffice; barrier is cheap here
  const int qg = b * 2048 + qbase + wid * 32;
#pragma unroll
  for (int a = 0; a < 4; a++) {
    f32x4 siv = *reinterpret_cast<const f32x4*>(&Sl[wid][a * 8 + hsel * 4]);
#pragma unroll
    for (int rr = 0; rr < 4; rr++) {
      const int row = qg + a * 8 + hsel * 4 + rr;
#pragma unroll
      for (int dI = 0; dI < 2; dI++)
        O[(size_t)row * 1024 + h * 64 + dI * 32 + l31] =
            (bf16_t)(oacc[dI][a * 4 + rr] * siv[rr]);
    }
  }
}

// ---------------------------------------------------------------------------
extern "C" void kernel_launch(void* const* d_in, const int* in_sizes, int n_in,
                              void* d_out, int out_size, void* d_ws, size_t ws_size,
                              hipStream_t stream) {
  const float* q  = (const float*)d_in[0];
  const float* k  = (const float*)d_in[1];
  const float* v  = (const float*)d_in[2];
  const float* wq = (const float*)d_in[3];
  const float* bq = (const float*)d_in[4];
  const float* wk = (const float*)d_in[5];
  const float* bk = (const float*)d_in[6];
  const float* wv = (const float*)d_in[7];
  const float* bv = (const float*)d_in[8];
  const float* wo = (const float*)d_in[9];
  const float* bo = (const float*)d_in[10];

  char* ws = (char*)d_ws;
  const size_t MB = 1024 * 1024;
  bf16_t* qb  = (bf16_t*)(ws + 0 * MB);    // 8 MB  (later reused as AO)
  bf16_t* kb  = (bf16_t*)(ws + 8 * MB);    // 8 MB  (later reused as VT)
  bf16_t* vb  = (bf16_t*)(ws + 16 * MB);   // 8 MB
  bf16_t* QP  = (bf16_t*)(ws + 24 * MB);   // 8 MB
  bf16_t* KP  = (bf16_t*)(ws + 32 * MB);   // 8 MB
  bf16_t* VP  = (bf16_t*)(ws + 40 * MB);   // 8 MB
  bf16_t* wqb = (bf16_t*)(ws + 48 * MB);   // 2 MB
  bf16_t* wkb = (bf16_t*)(ws + 50 * MB);   // 2 MB
  bf16_t* wvb = (bf16_t*)(ws + 52 * MB);   // 2 MB
  bf16_t* wob = (bf16_t*)(ws + 54 * MB);   // 2 MB
  bf16_t* VTb = (bf16_t*)(ws + 8 * MB);    // reuse kb (dead after K-proj)
  bf16_t* AO  = (bf16_t*)(ws + 0 * MB);    // reuse qb (dead after Q-proj)

  const float QSCALE = 0.125f * 1.44269504089f;  // 1/sqrt(64) * log2(e)

  cast_all<<<dim3(4096, 7), 256, 0, stream>>>(q, k, v, wq, wk, wv, wo,
                                              qb, kb, vb, wqb, wkb, wvb, wob);
  qkv_gemm<<<768, 256, 0, stream>>>(qb, kb, vb, wqb, wkb, wvb, bq, bk, bv,
                                    QP, KP, VP, QSCALE);
  transpose_v64<<<dim3(32, 32), 256, 0, stream>>>(VP, VTb);
  attn_fwd<<<512, 256, 0, stream>>>(QP, KP, VTb, AO);
  out_gemm<<<256, 256, 0, stream>>>(AO, wob, bo, (float*)d_out);
}

// Round 6
// 247.127 us; speedup vs baseline: 1.0189x; 1.0189x over previous
//
#include <hip/hip_runtime.h>

typedef __bf16 bf16_t;
typedef __bf16 bf16x8 __attribute__((ext_vector_type(8)));
typedef __bf16 bf16x4 __attribute__((ext_vector_type(4)));
typedef float f32x4 __attribute__((ext_vector_type(4)));

#define MFMA16(a, b, c) __builtin_amdgcn_mfma_f32_16x16x32_bf16((a), (b), (c), 0, 0, 0)

#define GLOAD_LDS16(gsrc, ldst)                                                     \
  __builtin_amdgcn_global_load_lds(                                                 \
      (const __attribute__((address_space(1))) void*)(gsrc),                        \
      (__attribute__((address_space(3))) void*)(ldst), 16, 0, 0)

// ---------------------------------------------------------------------------
// Cast fp32 -> bf16 for all 7 arrays in one dispatch.
// ---------------------------------------------------------------------------
__global__ __launch_bounds__(256) void cast_all(
    const float* __restrict__ s0, const float* __restrict__ s1, const float* __restrict__ s2,
    const float* __restrict__ s3, const float* __restrict__ s4, const float* __restrict__ s5,
    const float* __restrict__ s6,
    bf16_t* __restrict__ d0, bf16_t* __restrict__ d1, bf16_t* __restrict__ d2,
    bf16_t* __restrict__ d3, bf16_t* __restrict__ d4, bf16_t* __restrict__ d5,
    bf16_t* __restrict__ d6) {
  const int a = blockIdx.y;
  const float* s = a == 0 ? s0 : a == 1 ? s1 : a == 2 ? s2 : a == 3 ? s3
                 : a == 4 ? s4 : a == 5 ? s5 : s6;
  bf16_t* d = a == 0 ? d0 : a == 1 ? d1 : a == 2 ? d2 : a == 3 ? d3
            : a == 4 ? d4 : a == 5 ? d5 : d6;
  const int n = a < 3 ? (2 * 2048 * 1024) : (1024 * 1024);
  int i = (blockIdx.x * 256 + threadIdx.x) * 4;
  if (i >= n) return;
  float4 v = *reinterpret_cast<const float4*>(s + i);
  bf16x4 o;
  o[0] = (bf16_t)v.x; o[1] = (bf16_t)v.y; o[2] = (bf16_t)v.z; o[3] = (bf16_t)v.w;
  *reinterpret_cast<bf16x4*>(d + i) = o;
}

// ---------------------------------------------------------------------------
// NT GEMM core, 3-buffer 2-deep prefetch: C[.,1024] = A*B^T + bias.
// Tile 128 x (NFRAG*32), BK=32, 4 waves (2x2), 16x16x32 MFMA.
// Per iter: issue stage(t+2) -> vmcnt(2*LOADS) -> s_barrier -> MFMA -> s_barrier.
// Two stages always in flight => memory latency spans two compute iterations.
// ---------------------------------------------------------------------------
template <int OUTF32, int NFRAG>   // NFRAG: B-frags per wave (4 -> BN=128, 2 -> BN=64)
__device__ __forceinline__ void gemm_core3(
    const bf16_t* __restrict__ A, const bf16_t* __restrict__ B,
    const float* __restrict__ bias, void* __restrict__ Cout,
    int bm, int bn, float scalep, bf16_t* __restrict__ As, bf16_t* __restrict__ Bs) {
  const int tid = threadIdx.x, lane = tid & 63, wid = tid >> 6;
  const int wr = wid >> 1, wc = wid & 1;
  const int l15 = lane & 15, g = lane >> 4;
  f32x4 acc[4][NFRAG] = {};

  constexpr int ABUF = 4096;            // elems per A buffer (128 x 32)
  constexpr int BBUF = NFRAG * 1024;    // elems per B buffer

  // staging: instr covers 16 rows (4 lanes/row, 16B granule each)
  const int arow = wid * 16 + (lane >> 2);
  const int sc = (lane & 3) * 8;
  const bf16_t* Ap0 = A + (size_t)(bm + arow) * 1024 + sc;
  const bf16_t* Ap1 = Ap0 + (size_t)64 * 1024;
  const bf16_t* Bp0 = B + (size_t)(bn + arow) * 1024 + sc;
  const bf16_t* Bp1 = Bp0 + (size_t)64 * 1024;

  auto stage = [&](int k0, int buf) {
    bf16_t* Ad = As + buf * ABUF;
    bf16_t* Bd = Bs + buf * BBUF;
    GLOAD_LDS16(Ap0 + k0, Ad + wid * 512);
    GLOAD_LDS16(Ap1 + k0, Ad + 2048 + wid * 512);
    GLOAD_LDS16(Bp0 + k0, Bd + wid * 512);
    if constexpr (NFRAG == 4) GLOAD_LDS16(Bp1 + k0, Bd + 2048 + wid * 512);
  };

  stage(0, 0);
  stage(32, 1);
  for (int t = 0; t < 32; t++) {
    const int kn = (t < 30) ? (t + 2) * 32 : 0;   // clamped dummy at tail
    stage(kn, (t + 2) % 3);
    if constexpr (NFRAG == 4)
      asm volatile("s_waitcnt vmcnt(8)" ::: "memory");
    else
      asm volatile("s_waitcnt vmcnt(6)" ::: "memory");
    __builtin_amdgcn_s_barrier();
    __builtin_amdgcn_sched_barrier(0);
    const bf16_t* Ab = As + (t % 3) * ABUF;
    const bf16_t* Bb = Bs + (t % 3) * BBUF;
    bf16x8 af[4], bfr[NFRAG];
#pragma unroll
    for (int mi = 0; mi < 4; mi++)
      af[mi] = *reinterpret_cast<const bf16x8*>(&Ab[(wr * 64 + mi * 16 + l15) * 32 + g * 8]);
#pragma unroll
    for (int ni = 0; ni < NFRAG; ni++)
      bfr[ni] = *reinterpret_cast<const bf16x8*>(
          &Bb[(wc * (NFRAG * 16) + ni * 16 + l15) * 32 + g * 8]);
    __builtin_amdgcn_s_setprio(1);
#pragma unroll
    for (int mi = 0; mi < 4; mi++)
#pragma unroll
      for (int ni = 0; ni < NFRAG; ni++)
        acc[mi][ni] = MFMA16(af[mi], bfr[ni], acc[mi][ni]);
    __builtin_amdgcn_s_setprio(0);
    __builtin_amdgcn_sched_barrier(0);
    __builtin_amdgcn_s_barrier();
  }

#pragma unroll
  for (int mi = 0; mi < 4; mi++)
#pragma unroll
    for (int ni = 0; ni < NFRAG; ni++) {
      const int row = bm + wr * 64 + mi * 16 + g * 4;
      const int col = bn + wc * (NFRAG * 16) + ni * 16 + l15;
      const float bv = bias[col];
#pragma unroll
      for (int r = 0; r < 4; r++) {
        float v = (acc[mi][ni][r] + bv) * scalep;
        if (OUTF32)
          reinterpret_cast<float*>(Cout)[(size_t)(row + r) * 1024 + col] = v;
        else
          reinterpret_cast<bf16_t*>(Cout)[(size_t)(row + r) * 1024 + col] = (bf16_t)v;
      }
    }
}

// Fused Q/K/V projection: 768 blocks (3 matrices x 32m x 8n), XCD-swizzled.
__global__ __launch_bounds__(256) void qkv_gemm(
    const bf16_t* __restrict__ qb, const bf16_t* __restrict__ kb, const bf16_t* __restrict__ vb,
    const bf16_t* __restrict__ wqb, const bf16_t* __restrict__ wkb, const bf16_t* __restrict__ wvb,
    const float* __restrict__ bq, const float* __restrict__ bk, const float* __restrict__ bv,
    bf16_t* __restrict__ QP, bf16_t* __restrict__ KP, bf16_t* __restrict__ VP, float qscale) {
  __shared__ bf16_t As[3 * 4096];
  __shared__ bf16_t Bs[3 * 4096];
  const int id = blockIdx.x;
  const int sw = (id & 7) * 96 + (id >> 3);
  const int z = sw >> 8, rem = sw & 255;
  const int by = rem >> 3, bx = rem & 7;
  const bf16_t* A = z == 0 ? qb : z == 1 ? kb : vb;
  const bf16_t* B = z == 0 ? wqb : z == 1 ? wkb : wvb;
  const float* bias = z == 0 ? bq : z == 1 ? bk : bv;
  bf16_t* C = z == 0 ? QP : z == 1 ? KP : VP;
  gemm_core3<0, 4>(A, B, bias, C, by * 128, bx * 128, z == 0 ? qscale : 1.0f, As, Bs);
}

// Output projection -> fp32, 512 blocks (32m x 16n of 128x64 tiles).
__global__ __launch_bounds__(256) void out_gemm(
    const bf16_t* __restrict__ A, const bf16_t* __restrict__ B,
    const float* __restrict__ bias, float* __restrict__ C) {
  __shared__ bf16_t As[3 * 4096];
  __shared__ bf16_t Bs[3 * 2048];
  const int id = blockIdx.x;
  const int sw = (id & 7) * 64 + (id >> 3);
  const int by = sw >> 4, bx = sw & 15;
  gemm_core3<1, 2>(A, B, bias, C, by * 128, bx * 64, 1.0f, As, Bs);
}

// ---------------------------------------------------------------------------
// V transpose: VT[b*16+h][d][s] = VP[b][s][h*64+d]
// ---------------------------------------------------------------------------
__global__ __launch_bounds__(256) void transpose_v64(
    const bf16_t* __restrict__ VP, bf16_t* __restrict__ VT) {
  __shared__ bf16_t t[64][72];
  const int tid = threadIdx.x;
  const int bh = blockIdx.y, b = bh >> 4, h = bh & 15;
  const int sbase = blockIdx.x * 64;
#pragma unroll
  for (int i = 0; i < 2; i++) {
    int c = tid + i * 256;
    int r = c >> 3, cc = (c & 7) * 8;
    *reinterpret_cast<bf16x8*>(&t[r][cc]) =
        *reinterpret_cast<const bf16x8*>(&VP[(size_t)(b * 2048 + sbase + r) * 1024 + h * 64 + cc]);
  }
  __syncthreads();
#pragma unroll
  for (int i = 0; i < 2; i++) {
    int c = tid + i * 256;
    int d = c >> 3, scc = (c & 7) * 8;
    bf16x8 v;
#pragma unroll
    for (int j = 0; j < 8; j++) v[j] = t[scc + j][d];
    *reinterpret_cast<bf16x8*>(&VT[(size_t)(bh * 64 + d) * 2048 + sbase + scc]) = v;
  }
}

// ---------------------------------------------------------------------------
// Flash attention fwd v5: back to the 16x16 v3 structure, scaled out.
// 4 waves x 16 q-rows (QBLK=64), KVBLK=64, grid 1024 (4 blocks/CU).
// Swapped QK^T (lane owns q=l15); max-free exp2-domain softmax (scores
// pre-scaled by Q-projection); K/V double-buffered via global_load_lds
// (pre-swizzled source, XOR-swizzled reads); counted vmcnt(4) + raw
// s_barrier pair per tile (prefetch stays in flight across the barrier).
// ---------------------------------------------------------------------------
__global__ __launch_bounds__(256) void attn_fwd(
    const bf16_t* __restrict__ Q, const bf16_t* __restrict__ K,
    const bf16_t* __restrict__ VT, bf16_t* __restrict__ O) {
  __shared__ bf16_t Kl[2 * 4096];   // [kc][d] tiles, 16 KB
  __shared__ bf16_t Vl[2 * 4096];   // [d][kc] tiles, 16 KB
  __shared__ bf16_t Pl[4][1024];    // per-wave [q=16][kc=64], 8 KB
  const int tid = threadIdx.x, lane = tid & 63, wid = tid >> 6;
  const int l15 = lane & 15, g = lane >> 4, l7 = l15 & 7;
  const int id = blockIdx.x;
  const int sw = (id & 7) * 128 + (id >> 3);   // bijective XCD swizzle (1024 blocks)
  const int bh = sw >> 5, qblk = sw & 31;      // each bh contiguous within an XCD slice
  const int b = bh >> 4, h = bh & 15;
  const int qbase = qblk * 64;

  const int qrow = b * 2048 + qbase + wid * 16 + l15;
  const bf16x8 qf0 = *reinterpret_cast<const bf16x8*>(&Q[(size_t)qrow * 1024 + h * 64 + g * 8]);
  const bf16x8 qf1 = *reinterpret_cast<const bf16x8*>(&Q[(size_t)qrow * 1024 + h * 64 + 32 + g * 8]);

  // staging: wave wid covers K/V rows [wid*16, wid*16+16), 2 instrs per array
  const int srow = lane >> 3;                // row within 8-row group
  const int sg = (lane & 7) ^ srow;          // pre-swizzled source granule
  const bf16_t* Ksrc = K + (size_t)(b * 2048 + wid * 16 + srow) * 1024 + h * 64 + sg * 8;
  const bf16_t* Vsrc = VT + (size_t)(bh * 64 + wid * 16 + srow) * 2048 + sg * 8;

  auto stage = [&](int kt, int buf) {
    bf16_t* Kd = Kl + buf * 4096 + wid * 1024;
    bf16_t* Vd = Vl + buf * 4096 + wid * 1024;
    GLOAD_LDS16(Ksrc + (size_t)kt * 1024, Kd);
    GLOAD_LDS16(Ksrc + (size_t)(kt + 8) * 1024, Kd + 512);
    GLOAD_LDS16(Vsrc + kt, Vd);
    GLOAD_LDS16(Vsrc + kt + 8 * 2048, Vd + 512);
  };

  float ssum = 0.0f;
  f32x4 oacc[4] = {};

  stage(0, 0);
  for (int t = 0; t < 32; t++) {
    const int ktn = (t < 31) ? (t + 1) * 64 : 0;   // dummy re-stage at tail
    stage(ktn, (t + 1) & 1);
    asm volatile("s_waitcnt vmcnt(4)" ::: "memory");
    __builtin_amdgcn_s_barrier();
    __builtin_amdgcn_sched_barrier(0);
    const bf16_t* Kb = Kl + (t & 1) * 4096;
    const bf16_t* Vb = Vl + (t & 1) * 4096;

    // QK^T swapped: lane owns q=l15; sacc[ni] reg r <-> kc = ni*16 + g*4 + r
    f32x4 sacc[4] = {};
    __builtin_amdgcn_s_setprio(1);
#pragma unroll
    for (int ni = 0; ni < 4; ni++) {
      const int krow = (ni * 16 + l15) * 64;
      bf16x8 kf0 = *reinterpret_cast<const bf16x8*>(&Kb[krow + ((g ^ l7) * 8)]);
      bf16x8 kf1 = *reinterpret_cast<const bf16x8*>(&Kb[krow + (((4 + g) ^ l7) * 8)]);
      sacc[ni] = MFMA16(kf0, qf0, sacc[ni]);
      sacc[ni] = MFMA16(kf1, qf1, sacc[ni]);
    }
    __builtin_amdgcn_s_setprio(0);

    // max-free softmax: P = exp2(score'), row-sum for normalization
    float rs = 0.0f;
#pragma unroll
    for (int ni = 0; ni < 4; ni++)
#pragma unroll
      for (int r = 0; r < 4; r++) {
        float e = exp2f(sacc[ni][r]);
        sacc[ni][r] = e;
        rs += e;
      }
    rs += __shfl_xor(rs, 16);
    rs += __shfl_xor(rs, 32);
    ssum += rs;

    // P -> per-wave LDS (swizzled granules, packed b64); same-wave only
#pragma unroll
    for (int ni = 0; ni < 4; ni++) {
      bf16x4 pv;
#pragma unroll
      for (int r = 0; r < 4; r++) pv[r] = (bf16_t)sacc[ni][r];
      *reinterpret_cast<bf16x4*>(
          &Pl[wid][l15 * 64 + (((2 * ni + (g >> 1)) ^ l7) * 8) + (g & 1) * 4]) = pv;
    }

    // PV: O[q][d] += P[q][kc] * V[kc][d]
    __builtin_amdgcn_s_setprio(1);
#pragma unroll
    for (int c = 0; c < 2; c++) {
      const int gp = ((c * 4 + g) ^ l7) * 8;
      bf16x8 pf = *reinterpret_cast<const bf16x8*>(&Pl[wid][l15 * 64 + gp]);
#pragma unroll
      for (int dn = 0; dn < 4; dn++) {
        bf16x8 vf = *reinterpret_cast<const bf16x8*>(&Vb[(dn * 16 + l15) * 64 + gp]);
        oacc[dn] = MFMA16(pf, vf, oacc[dn]);
      }
    }
    __builtin_amdgcn_s_setprio(0);
    __builtin_amdgcn_sched_barrier(0);
    __builtin_amdgcn_s_barrier();
  }

  // epilogue: O rows q = g*4 + r; ssum lives replicated across g at lane l15=q
  float si[4];
#pragma unroll
  for (int r = 0; r < 4; r++) si[r] = 1.0f / __shfl(ssum, g * 4 + r);
  const int orow = b * 2048 + qbase + wid * 16 + g * 4;
#pragma unroll
  for (int dn = 0; dn < 4; dn++)
#pragma unroll
    for (int r = 0; r < 4; r++)
      O[(size_t)(orow + r) * 1024 + h * 64 + dn * 16 + l15] = (bf16_t)(oacc[dn][r] * si[r]);
}

// ---------------------------------------------------------------------------
extern "C" void kernel_launch(void* const* d_in, const int* in_sizes, int n_in,
                              void* d_out, int out_size, void* d_ws, size_t ws_size,
                              hipStream_t stream) {
  const float* q  = (const float*)d_in[0];
  const float* k  = (const float*)d_in[1];
  const float* v  = (const float*)d_in[2];
  const float* wq = (const float*)d_in[3];
  const float* bq = (const float*)d_in[4];
  const float* wk = (const float*)d_in[5];
  const float* bk = (const float*)d_in[6];
  const float* wv = (const float*)d_in[7];
  const float* bv = (const float*)d_in[8];
  const float* wo = (const float*)d_in[9];
  const float* bo = (const float*)d_in[10];

  char* ws = (char*)d_ws;
  const size_t MB = 1024 * 1024;
  bf16_t* qb  = (bf16_t*)(ws + 0 * MB);    // 8 MB  (later reused as AO)
  bf16_t* kb  = (bf16_t*)(ws + 8 * MB);    // 8 MB  (later reused as VT)
  bf16_t* vb  = (bf16_t*)(ws + 16 * MB);   // 8 MB
  bf16_t* QP  = (bf16_t*)(ws + 24 * MB);   // 8 MB
  bf16_t* KP  = (bf16_t*)(ws + 32 * MB);   // 8 MB
  bf16_t* VP  = (bf16_t*)(ws + 40 * MB);   // 8 MB
  bf16_t* wqb = (bf16_t*)(ws + 48 * MB);   // 2 MB
  bf16_t* wkb = (bf16_t*)(ws + 50 * MB);   // 2 MB
  bf16_t* wvb = (bf16_t*)(ws + 52 * MB);   // 2 MB
  bf16_t* wob = (bf16_t*)(ws + 54 * MB);   // 2 MB
  bf16_t* VTb = (bf16_t*)(ws + 8 * MB);    // reuse kb (dead after K-proj)
  bf16_t* AO  = (bf16_t*)(ws + 0 * MB);    // reuse qb (dead after Q-proj)

  const float QSCALE = 0.125f * 1.44269504089f;  // 1/sqrt(64) * log2(e)

  cast_all<<<dim3(4096, 7), 256, 0, stream>>>(q, k, v, wq, wk, wv, wo,
                                              qb, kb, vb, wqb, wkb, wvb, wob);
  qkv_gemm<<<768, 256, 0, stream>>>(qb, kb, vb, wqb, wkb, wvb, bq, bk, bv,
                                    QP, KP, VP, QSCALE);
  transpose_v64<<<dim3(32, 32), 256, 0, stream>>>(VP, VTb);
  attn_fwd<<<1024, 256, 0, stream>>>(QP, KP, VTb, AO);
  out_gemm<<<512, 256, 0, stream>>>(AO, wob, bo, (float*)d_out);
}